// Round 5
// baseline (699.108 us; speedup 1.0000x reference)
//
#include <hip/hip_runtime.h>
#include <hip/hip_bf16.h>
#include <math.h>

typedef unsigned short u16;
typedef unsigned int u32;
typedef __attribute__((ext_vector_type(8))) short bf16x8;
typedef __attribute__((ext_vector_type(4))) float f32x4;

// B=4, T=2048, D=1024, H=16, DK=64, DV=128, CHUNK=64, N_CHUNKS=32

__device__ __forceinline__ u16 f2bf(float f) {
  union { float f; unsigned u; } a; a.f = f;
  unsigned u = a.u;
  unsigned r = (u + 0x7fffu + ((u >> 16) & 1u)) >> 16;
  return (u16)r;
}
__device__ __forceinline__ float bf2f(u16 s) {
  union { unsigned u; float f; } a; a.u = ((unsigned)s) << 16; return a.f;
}

__global__ void k_sentinel(float* out) {
  if (threadIdx.x == 0 && blockIdx.x == 0) out[0] = 1.0e6f;
}

// exact split: f32 -> bf16 hi + bf16 lo (hi+lo == f to ~2^-16 rel)
__device__ __forceinline__ void split8r(const float* t, bf16x8& hi, bf16x8& lo) {
#pragma unroll
  for (int m = 0; m < 8; ++m) {
    union { float f; u32 u; } c; c.f = t[m];
    union { u32 u; float f; } hf; hf.u = c.u & 0xffff0000u;
    union { float f; u32 u; } lw; lw.f = t[m] - hf.f;
    hi[m] = (short)(u16)(c.u >> 16);
    lo[m] = (short)(u16)(lw.u >> 16);
  }
}
__device__ __forceinline__ void split8p(const float* __restrict__ p, bf16x8& hi, bf16x8& lo) {
  f32x4 a = *(const f32x4*)p;
  f32x4 b = *(const f32x4*)(p + 4);
  float t[8];
  t[0]=a[0]; t[1]=a[1]; t[2]=a[2]; t[3]=a[3]; t[4]=b[0]; t[5]=b[1]; t[6]=b[2]; t[7]=b[3];
  split8r(t, hi, lo);
}

// async global->LDS, 16B per lane; lds base must be wave-uniform (HW adds lane*16)
__device__ __forceinline__ void gload16(const u16* g, u16* l) {
  __builtin_amdgcn_global_load_lds(
      (const __attribute__((address_space(1))) unsigned int*)g,
      (__attribute__((address_space(3))) unsigned int*)l, 16, 0, 0);
}

// ---------- x f32 -> bf16 ----------
__global__ __launch_bounds__(256) void k_cvt_x(const float* __restrict__ src, u16* __restrict__ dst) {
  int i = blockIdx.x * 256 + threadIdx.x;
  float4 v = ((const float4*)src)[i];
  ushort4 o;
  o.x = f2bf(v.x); o.y = f2bf(v.y); o.z = f2bf(v.z); o.w = f2bf(v.w);
  ((ushort4*)dst)[i] = o;
}

// ---------- W [K][N] f32 -> [N][K] bf16 (tiled transpose) ----------
__global__ __launch_bounds__(256) void k_transpose(const float* __restrict__ src, u16* __restrict__ dst,
                                                   int K, int N) {
  __shared__ float tile[32][33];
  int n0 = blockIdx.x * 32, k0 = blockIdx.y * 32;
  int tx = threadIdx.x & 31, ty = threadIdx.x >> 5;
  for (int r = 0; r < 32; r += 8)
    tile[ty + r][tx] = src[(size_t)(k0 + ty + r) * N + n0 + tx];
  __syncthreads();
  for (int r = 0; r < 32; r += 8)
    dst[(size_t)(n0 + ty + r) * K + k0 + tx] = f2bf(tile[tx][ty + r]);
}

// ---------- bf16 GEMM via global_load_lds: C[M][N] = A[M][K] * Bt[N][K]^T ----------
// MODE 0: f32 out; 1: bf16 out; 2: f32 out + fused RoPE (q cols <1024 scaled 0.125)
template <int MODE>
__global__ __launch_bounds__(256) void k_gemm(const u16* __restrict__ A, const u16* __restrict__ Bt,
                                              void* __restrict__ Cv, int N, int K) {
  __shared__ __attribute__((aligned(16))) u16 As[128 * 32];
  __shared__ __attribute__((aligned(16))) u16 Bs[128 * 32];
  // XCD-aware swizzle (nwg divisible by 8 for all our grids)
  int nbx = gridDim.x;
  int id = blockIdx.y * nbx + blockIdx.x;
  int cpx = (nbx * gridDim.y) >> 3;
  int sw = (id & 7) * cpx + (id >> 3);
  int bx = sw % nbx, by = sw / nbx;
  int i0 = by * 128, n0 = bx * 128;
  int tid = threadIdx.x;
  int lane = tid & 63, w = tid >> 6;
  int wr = (w >> 1) * 64, wc = (w & 1) * 64;
  int srow = lane >> 2, scol = (lane & 3) * 8;   // staging: 16 rows x 32 cols per 1KB seg
  f32x4 acc[4][4];
#pragma unroll
  for (int m = 0; m < 4; ++m)
#pragma unroll
    for (int n = 0; n < 4; ++n) acc[m][n] = (f32x4){0.f, 0.f, 0.f, 0.f};
  int fr = lane & 15, kb = (lane >> 4) * 8;
  for (int k0 = 0; k0 < K; k0 += 32) {
    __syncthreads();
#pragma unroll
    for (int q = 0; q < 2; ++q) {
      int s = w * 2 + q;
      gload16(&A[(size_t)(i0 + s * 16 + srow) * K + k0 + scol], &As[s * 512]);
      gload16(&Bt[(size_t)(n0 + s * 16 + srow) * K + k0 + scol], &Bs[s * 512]);
    }
    asm volatile("s_waitcnt vmcnt(0)" ::: "memory");
    __syncthreads();
    bf16x8 af[4], bfr[4];
#pragma unroll
    for (int m = 0; m < 4; ++m) af[m] = *(const bf16x8*)&As[(wr + m * 16 + fr) * 32 + kb];
#pragma unroll
    for (int n = 0; n < 4; ++n) bfr[n] = *(const bf16x8*)&Bs[(wc + n * 16 + fr) * 32 + kb];
#pragma unroll
    for (int m = 0; m < 4; ++m)
#pragma unroll
      for (int n = 0; n < 4; ++n)
        acc[m][n] = __builtin_amdgcn_mfma_f32_16x16x32_bf16(af[m], bfr[n], acc[m][n], 0, 0, 0);
  }
  int rb = (lane >> 4) * 4, cb = lane & 15;
  if (MODE == 2) {
    // fused RoPE: pair (col, col+32) within each 64-col head; frag n pairs with n+2
    float scale = (n0 < 1024) ? 0.125f : 1.0f;
#pragma unroll
    for (int m = 0; m < 4; ++m)
#pragma unroll
      for (int r = 0; r < 4; ++r) {
        int gr = i0 + wr + m * 16 + rb + r;
        int t = gr & 2047;
#pragma unroll
        for (int n = 0; n < 2; ++n) {
          int gc = n0 + wc + n * 16 + cb;
          int ii = gc & 31;   // (n0+wc)%64==0 -> ii = cb+16n in [0,32)
          float invf = powf(10000.f, -(float)ii * (1.f / 32.f));
          float ang = (float)t * invf;
          float sv = sinf(ang), cv = cosf(ang);
          float q1 = acc[m][n][r], q2 = acc[m][n + 2][r];
          ((float*)Cv)[(size_t)gr * N + gc]      = (q1 * cv - q2 * sv) * scale;
          ((float*)Cv)[(size_t)gr * N + gc + 32] = (q2 * cv + q1 * sv) * scale;
        }
      }
  } else {
#pragma unroll
    for (int m = 0; m < 4; ++m)
#pragma unroll
      for (int n = 0; n < 4; ++n) {
        int gr = i0 + wr + m * 16 + rb;
        int gc = n0 + wc + n * 16 + cb;
#pragma unroll
        for (int r = 0; r < 4; ++r) {
          float v = acc[m][n][r];
          if (MODE == 1) ((u16*)Cv)[(size_t)(gr + r) * N + gc] = f2bf(v);
          else           ((float*)Cv)[(size_t)(gr + r) * N + gc] = v;
        }
      }
  }
}

// ---------- Fused retention v4: 8 waves, e-strip split, grouped LDS layouts ----------
// 256 blocks = (rq 4) x (bh 64). Block owns rows gi = rq*16+[0,16) of each chunk.
// Wave w: attn partial (ct=w&3, kh=w>>2); o1/o2/S-upd for e-strip [16w,16w+16).
// S kept as f32 frag accumulators (full 64d x strip); bf16 hi/lo copy in grouped LDS.
__global__ __launch_bounds__(512) void k_retention(const float* __restrict__ qk, const u16* __restrict__ vg,
                                                   const float* __restrict__ gnw, u16* __restrict__ og) {
  int bh = blockIdx.x & 63, rq = blockIdx.x >> 6;
  int h = bh & 15, b = bh >> 4;
  int gi0 = rq * 16;

  __shared__ __attribute__((aligned(16))) float qs[16][68];      // q rows [i][d]
  __shared__ __attribute__((aligned(16))) float ks[64][68];      // k row-major [j][d]
  __shared__ __attribute__((aligned(16))) float attnf[2][16][68];// qk^T kh-partials [kh][i][j]
  __shared__ __attribute__((aligned(16))) u16 vst[128][88];      // v^T [e][j]
  __shared__ __attribute__((aligned(16))) u16 kta_h[8][520];     // (kdec*k)^T hi, [j>>3][d*8+(j&7)]
  __shared__ __attribute__((aligned(16))) u16 kta_l[8][520];
  __shared__ __attribute__((aligned(16))) u16 sst_h[8][1040];    // S^T hi, [d>>3][e*8+(d&7)]
  __shared__ __attribute__((aligned(16))) u16 sst_l[8][1040];
  __shared__ float dpow[72];
  __shared__ float ssred[8][16];

  int tid = threadIdx.x;
  int w = tid >> 6, l = tid & 63;
  int fr = l & 15, fq = l >> 4;
  float gamma = 1.f - exp2f(-5.f - (float)h);
  if (tid <= 64) dpow[tid] = powf(gamma, (float)tid);
  for (int c = tid; c < 8 * 520; c += 512) { ((u32*)sst_h)[c] = 0; ((u32*)sst_l)[c] = 0; }
  __syncthreads();
  float cdec = dpow[64];

  int e0 = w * 16;
  int ct = w & 3, kha = w >> 2;        // attn роль
  float gww = gnw[e0 + fr];
  int khmax = (gi0 + 15 < 32) ? 1 : 2; // o1 j-halves needed
  bool attn_live = (16 * ct <= gi0 + 15);

  // staging roles
  int sj = tid >> 3, sdg = (tid & 7) * 8;        // k rows
  int vjp = tid & 31, ve8 = (tid >> 5) * 8;      // v^T paired-u32

  f32x4 Sacc[4];
#pragma unroll
  for (int dt = 0; dt < 4; ++dt) Sacc[dt] = (f32x4){0.f, 0.f, 0.f, 0.f};

  for (int n = 0; n < 32; ++n) {
    int rowbase = b * 2048 + n * 64;
    // ---- phase 1: stage q, k (+grouped kdec*k^T), v^T ----
    if (tid < 256) {
      int i = tid >> 4, d4 = (tid & 15) * 4;
      *(f32x4*)&qs[i][d4] = *(const f32x4*)&qk[(size_t)(rowbase + gi0 + i) * 2048 + h * 64 + d4];
    }
    {
      const float* kr = &qk[(size_t)(rowbase + sj) * 2048 + 1024 + h * 64 + sdg];
      f32x4 ka = *(const f32x4*)kr;
      f32x4 kb2 = *(const f32x4*)(kr + 4);
      *(f32x4*)&ks[sj][sdg] = ka;
      *(f32x4*)&ks[sj][sdg + 4] = kb2;
      float kdv = dpow[63 - sj];
      float kd[8];
#pragma unroll
      for (int m = 0; m < 4; ++m) { kd[m] = ka[m] * kdv; kd[m + 4] = kb2[m] * kdv; }
      bf16x8 kh8, kl8;
      split8r(kd, kh8, kl8);
      int g = sj >> 3, s = sj & 7;
#pragma unroll
      for (int m = 0; m < 8; ++m) {
        kta_h[g][(sdg + m) * 8 + s] = (u16)kh8[m];
        kta_l[g][(sdg + m) * 8 + s] = (u16)kl8[m];
      }
      const u16* vr = &vg[(size_t)(rowbase + 2 * vjp) * 4096 + h * 128 + ve8];
      bf16x8 va = *(const bf16x8*)vr;
      bf16x8 vb = *(const bf16x8*)(vr + 4096);
#pragma unroll
      for (int m = 0; m < 8; ++m)
        *(u32*)&vst[ve8 + m][2 * vjp] = (u32)(u16)va[m] | ((u32)(u16)vb[m] << 16);
    }
    __syncthreads();
    // ---- phase 2: attn partial (ct, kha): C[i][j-tile] over K=32 d-half ----
    {
      f32x4 at = (f32x4){0.f, 0.f, 0.f, 0.f};
      if (attn_live) {
        bf16x8 qh, ql, kbh, kbl;
        split8p(&qs[fr][kha * 32 + fq * 8], qh, ql);
        split8p(&ks[16 * ct + fr][kha * 32 + fq * 8], kbh, kbl);
        at = __builtin_amdgcn_mfma_f32_16x16x32_bf16(qh, kbh, at, 0, 0, 0);
        at = __builtin_amdgcn_mfma_f32_16x16x32_bf16(qh, kbl, at, 0, 0, 0);
        at = __builtin_amdgcn_mfma_f32_16x16x32_bf16(ql, kbh, at, 0, 0, 0);
      }
#pragma unroll
      for (int r = 0; r < 4; ++r) attnf[kha][fq * 4 + r][16 * ct + fr] = at[r];
    }
    __syncthreads();
    // ---- phase 3a: o1 = attn@v, o2 = q@S for e-strip ----
    f32x4 o1 = (f32x4){0.f, 0.f, 0.f, 0.f};
    f32x4 o2 = (f32x4){0.f, 0.f, 0.f, 0.f};
#pragma unroll
    for (int kh2 = 0; kh2 < 2; ++kh2) {
      bf16x8 qh, ql;
      split8p(&qs[fr][kh2 * 32 + fq * 8], qh, ql);
      bf16x8 sh = *(const bf16x8*)&sst_h[kh2 * 4 + fq][(e0 + fr) * 8];
      bf16x8 sl = *(const bf16x8*)&sst_l[kh2 * 4 + fq][(e0 + fr) * 8];
      o2 = __builtin_amdgcn_mfma_f32_16x16x32_bf16(qh, sh, o2, 0, 0, 0);
      o2 = __builtin_amdgcn_mfma_f32_16x16x32_bf16(qh, sl, o2, 0, 0, 0);
      o2 = __builtin_amdgcn_mfma_f32_16x16x32_bf16(ql, sh, o2, 0, 0, 0);
      if (kh2 < khmax) {
        float tmp[8];
        int gi = gi0 + fr;
#pragma unroll
        for (int m = 0; m < 8; ++m) {
          int kk = kh2 * 32 + fq * 8 + m;
          float raw = attnf[0][fr][kk] + attnf[1][fr][kk];
          int s = gi - kk;
          tmp[m] = (s >= 0) ? raw * dpow[s] : 0.f;
        }
        bf16x8 ath, atl;
        split8r(tmp, ath, atl);
        bf16x8 bv = *(const bf16x8*)&vst[e0 + fr][kh2 * 32 + fq * 8];
        o1 = __builtin_amdgcn_mfma_f32_16x16x32_bf16(ath, bv, o1, 0, 0, 0);
        o1 = __builtin_amdgcn_mfma_f32_16x16x32_bf16(atl, bv, o1, 0, 0, 0);
      }
    }
    float ofin[4], ssp[4];
#pragma unroll
    for (int r = 0; r < 4; ++r) {
      int gi = gi0 + fq * 4 + r;
      ofin[r] = o1[r] + dpow[gi + 1] * o2[r];
      ssp[r] = ofin[r] * ofin[r];
    }
#pragma unroll
    for (int r = 0; r < 4; ++r) {
      ssp[r] += __shfl_xor(ssp[r], 1, 64);
      ssp[r] += __shfl_xor(ssp[r], 2, 64);
      ssp[r] += __shfl_xor(ssp[r], 4, 64);
      ssp[r] += __shfl_xor(ssp[r], 8, 64);
    }
    if (fr == 0) {
#pragma unroll
      for (int r = 0; r < 4; ++r) ssred[w][fq * 4 + r] = ssp[r];
    }
    __syncthreads();
    // ---- phase 3b: rms + gate + store; then S-update ----
#pragma unroll
    for (int r = 0; r < 4; ++r) {
      int i16 = fq * 4 + r;
      float tot = 0.f;
#pragma unroll
      for (int w2 = 0; w2 < 8; ++w2) tot += ssred[w2][i16];
      float rms = rsqrtf(tot * (1.f / 128.f) + 1e-5f);
      int grow = rowbase + gi0 + i16;
      float g = bf2f(vg[(size_t)grow * 4096 + 2048 + h * 128 + e0 + fr]);
      float y = ofin[r] * rms * gww * (g / (1.f + expf(-g)));
      og[(size_t)grow * 2048 + h * 128 + e0 + fr] = f2bf(y);
    }
    if (n < 31) {
#pragma unroll
      for (int dt = 0; dt < 4; ++dt) {
#pragma unroll
        for (int r = 0; r < 4; ++r) Sacc[dt][r] *= cdec;
      }
#pragma unroll
      for (int kh2 = 0; kh2 < 2; ++kh2) {
        bf16x8 bv = *(const bf16x8*)&vst[e0 + fr][kh2 * 32 + fq * 8];
#pragma unroll
        for (int dt = 0; dt < 4; ++dt) {
          bf16x8 ah = *(const bf16x8*)&kta_h[kh2 * 4 + fq][(dt * 16 + fr) * 8];
          bf16x8 al = *(const bf16x8*)&kta_l[kh2 * 4 + fq][(dt * 16 + fr) * 8];
          Sacc[dt] = __builtin_amdgcn_mfma_f32_16x16x32_bf16(ah, bv, Sacc[dt], 0, 0, 0);
          Sacc[dt] = __builtin_amdgcn_mfma_f32_16x16x32_bf16(al, bv, Sacc[dt], 0, 0, 0);
        }
      }
      // write S^T hi/lo (grouped layout) for next chunk's o2
#pragma unroll
      for (int dt = 0; dt < 4; ++dt) {
        ushort4 wh, wl;
#pragma unroll
        for (int r = 0; r < 4; ++r) {
          union { float f; u32 u; } c; c.f = Sacc[dt][r];
          union { u32 u; float f; } hf; hf.u = c.u & 0xffff0000u;
          union { float f; u32 u; } lw; lw.f = Sacc[dt][r] - hf.f;
          ((u16*)&wh)[r] = (u16)(c.u >> 16);
          ((u16*)&wl)[r] = (u16)(lw.u >> 16);
        }
        int g = dt * 2 + (fq >> 1);
        int idx = (e0 + fr) * 8 + (fq & 1) * 4;
        *(ushort4*)&sst_h[g][idx] = wh;
        *(ushort4*)&sst_l[g][idx] = wl;
      }
    }
    __syncthreads();
  }
}

extern "C" void kernel_launch(void* const* d_in, const int* in_sizes, int n_in,
                              void* d_out, int out_size, void* d_ws, size_t ws_size,
                              hipStream_t stream) {
  const float* x   = (const float*)d_in[0];
  const float* Wq  = (const float*)d_in[1];
  const float* Wk  = (const float*)d_in[2];
  const float* Wv  = (const float*)d_in[3];
  const float* Wg  = (const float*)d_in[4];
  const float* Wo  = (const float*)d_in[5];
  const float* gnw = (const float*)d_in[6];
  float* out = (float*)d_out;

  const size_t MB = 1024 * 1024;
  char* ws = (char*)d_ws;
  u16*  xb   = (u16*)(ws + 0 * MB);
  u16*  Wqkb = (u16*)(ws + 16 * MB);
  u16*  Wvgb = (u16*)(ws + 20 * MB);
  float* qk  = (float*)(ws + 32 * MB);
  u16*  vg   = (u16*)(ws + 96 * MB);
  u16*  Wob  = (u16*)(ws + 160 * MB);
  u16*  og   = (u16*)(ws + 0 * MB);   // overlay (xb/Wqkb/Wvgb dead by then)
  const size_t NEED = 164 * MB;
  if (ws_size < NEED) {
    k_sentinel<<<1, 64, 0, stream>>>(out);
    return;
  }

  k_cvt_x<<<8192, 256, 0, stream>>>(x, xb);
  k_transpose<<<dim3(32, 32), 256, 0, stream>>>(Wq, Wqkb, 1024, 1024);
  k_transpose<<<dim3(32, 32), 256, 0, stream>>>(Wk, Wqkb + (size_t)1024 * 1024, 1024, 1024);
  k_transpose<<<dim3(64, 32), 256, 0, stream>>>(Wv, Wvgb, 1024, 2048);
  k_transpose<<<dim3(64, 32), 256, 0, stream>>>(Wg, Wvgb + (size_t)2048 * 1024, 1024, 2048);
  k_transpose<<<dim3(32, 64), 256, 0, stream>>>(Wo, Wob, 2048, 1024);

  k_gemm<2><<<dim3(16, 64), 256, 0, stream>>>(xb, Wqkb, qk, 2048, 1024);   // qk + fused RoPE
  k_gemm<1><<<dim3(32, 64), 256, 0, stream>>>(xb, Wvgb, vg, 4096, 1024);   // v|g bf16
  k_retention<<<256, 512, 0, stream>>>(qk, vg, gnw, og);
  k_gemm<0><<<dim3(8, 64), 256, 0, stream>>>(og, Wob, out, 1024, 2048);    // out
}

// Round 6
// 395.455 us; speedup vs baseline: 1.7679x; 1.7679x over previous
//
#include <hip/hip_runtime.h>
#include <hip/hip_bf16.h>
#include <math.h>

typedef unsigned short u16;
typedef unsigned int u32;
typedef __attribute__((ext_vector_type(8))) short bf16x8;
typedef __attribute__((ext_vector_type(4))) float f32x4;

// B=4, T=2048, D=1024, H=16, DK=64, DV=128, CHUNK=64, N_CHUNKS=32

__device__ __forceinline__ u16 f2bf(float f) {
  union { float f; unsigned u; } a; a.f = f;
  unsigned u = a.u;
  unsigned r = (u + 0x7fffu + ((u >> 16) & 1u)) >> 16;
  return (u16)r;
}
__device__ __forceinline__ float bf2f(u16 s) {
  union { unsigned u; float f; } a; a.u = ((unsigned)s) << 16; return a.f;
}

__global__ void k_sentinel(float* out) {
  if (threadIdx.x == 0 && blockIdx.x == 0) out[0] = 1.0e6f;
}

// exact split: f32 -> bf16 hi + bf16 lo (hi+lo == f to ~2^-16 rel)
__device__ __forceinline__ void split8r(const float* t, bf16x8& hi, bf16x8& lo) {
#pragma unroll
  for (int m = 0; m < 8; ++m) {
    union { float f; u32 u; } c; c.f = t[m];
    union { u32 u; float f; } hf; hf.u = c.u & 0xffff0000u;
    union { float f; u32 u; } lw; lw.f = t[m] - hf.f;
    hi[m] = (short)(u16)(c.u >> 16);
    lo[m] = (short)(u16)(lw.u >> 16);
  }
}
__device__ __forceinline__ void split8p(const float* __restrict__ p, bf16x8& hi, bf16x8& lo) {
  f32x4 a = *(const f32x4*)p;
  f32x4 b = *(const f32x4*)(p + 4);
  float t[8];
  t[0]=a[0]; t[1]=a[1]; t[2]=a[2]; t[3]=a[3]; t[4]=b[0]; t[5]=b[1]; t[6]=b[2]; t[7]=b[3];
  split8r(t, hi, lo);
}

// async global->LDS, 16B per lane; lds base wave-uniform (HW adds lane*16)
__device__ __forceinline__ void gload16(const u16* g, u16* l) {
  __builtin_amdgcn_global_load_lds(
      (const __attribute__((address_space(1))) unsigned int*)g,
      (__attribute__((address_space(3))) unsigned int*)l, 16, 0, 0);
}

// ---------- x f32 -> bf16 ----------
__global__ __launch_bounds__(256) void k_cvt_x(const float* __restrict__ src, u16* __restrict__ dst) {
  int i = blockIdx.x * 256 + threadIdx.x;
  float4 v = ((const float4*)src)[i];
  ushort4 o;
  o.x = f2bf(v.x); o.y = f2bf(v.y); o.z = f2bf(v.z); o.w = f2bf(v.w);
  ((ushort4*)dst)[i] = o;
}

// ---------- W [K][N] f32 -> [N][K] bf16 (tiled transpose) ----------
__global__ __launch_bounds__(256) void k_transpose(const float* __restrict__ src, u16* __restrict__ dst,
                                                   int K, int N) {
  __shared__ float tile[32][33];
  int n0 = blockIdx.x * 32, k0 = blockIdx.y * 32;
  int tx = threadIdx.x & 31, ty = threadIdx.x >> 5;
  for (int r = 0; r < 32; r += 8)
    tile[ty + r][tx] = src[(size_t)(k0 + ty + r) * N + n0 + tx];
  __syncthreads();
  for (int r = 0; r < 32; r += 8)
    dst[(size_t)(n0 + ty + r) * K + k0 + tx] = f2bf(tile[tx][ty + r]);
}

// ---------- bf16 GEMM via global_load_lds: C[M][N] = A[M][K] * Bt[N][K]^T ----------
// BF16OUT: write bf16, else f32. launch_bounds(...,2): target 2 waves/EU so the
// allocator keeps acc in AGPRs instead of squeezing to 64 VGPR (round-5 spill).
template <bool BF16OUT>
__global__ __launch_bounds__(256, 2) void k_gemm(const u16* __restrict__ A, const u16* __restrict__ Bt,
                                                 void* __restrict__ Cv, int N, int K) {
  __shared__ __attribute__((aligned(16))) u16 As[128 * 32];
  __shared__ __attribute__((aligned(16))) u16 Bs[128 * 32];
  // XCD-aware swizzle (all grids have nwg % 8 == 0)
  int nbx = gridDim.x;
  int id = blockIdx.y * nbx + blockIdx.x;
  int cpx = (nbx * gridDim.y) >> 3;
  int sw = (id & 7) * cpx + (id >> 3);
  int bx = sw % nbx, by = sw / nbx;
  int i0 = by * 128, n0 = bx * 128;
  int tid = threadIdx.x;
  int lane = tid & 63, w = tid >> 6;
  int wr = (w >> 1) * 64, wc = (w & 1) * 64;
  int srow = lane >> 2, scol = (lane & 3) * 8;   // staging: 16 rows x 32 cols per 1KB seg
  f32x4 acc[4][4];
#pragma unroll
  for (int m = 0; m < 4; ++m)
#pragma unroll
    for (int n = 0; n < 4; ++n) acc[m][n] = (f32x4){0.f, 0.f, 0.f, 0.f};
  int fr = lane & 15, kb = (lane >> 4) * 8;
  for (int k0 = 0; k0 < K; k0 += 32) {
    __syncthreads();
#pragma unroll
    for (int q = 0; q < 2; ++q) {
      int s = w * 2 + q;
      gload16(&A[(size_t)(i0 + s * 16 + srow) * K + k0 + scol], &As[s * 512]);
      gload16(&Bt[(size_t)(n0 + s * 16 + srow) * K + k0 + scol], &Bs[s * 512]);
    }
    asm volatile("s_waitcnt vmcnt(0)" ::: "memory");
    __syncthreads();
    bf16x8 af[4], bfr[4];
#pragma unroll
    for (int m = 0; m < 4; ++m) af[m] = *(const bf16x8*)&As[(wr + m * 16 + fr) * 32 + kb];
#pragma unroll
    for (int n = 0; n < 4; ++n) bfr[n] = *(const bf16x8*)&Bs[(wc + n * 16 + fr) * 32 + kb];
#pragma unroll
    for (int m = 0; m < 4; ++m)
#pragma unroll
      for (int n = 0; n < 4; ++n)
        acc[m][n] = __builtin_amdgcn_mfma_f32_16x16x32_bf16(af[m], bfr[n], acc[m][n], 0, 0, 0);
  }
  int rb = (lane >> 4) * 4, cb = lane & 15;
#pragma unroll
  for (int m = 0; m < 4; ++m)
#pragma unroll
    for (int n = 0; n < 4; ++n) {
      int gr = i0 + wr + m * 16 + rb;
      int gc = n0 + wc + n * 16 + cb;
#pragma unroll
      for (int r = 0; r < 4; ++r) {
        float v = acc[m][n][r];
        if (BF16OUT) ((u16*)Cv)[(size_t)(gr + r) * N + gc] = f2bf(v);
        else         ((float*)Cv)[(size_t)(gr + r) * N + gc] = v;
      }
    }
}

// ---------- RoPE in place (proven round-4 version) ----------
__global__ __launch_bounds__(256) void k_rope(float* __restrict__ qk) {
  int idx = blockIdx.x * 256 + threadIdx.x;
  int i = idx & 31;
  int row = idx >> 5;
  int t = row & 2047;
  float invf = powf(10000.f, -(float)i * (1.f / 32.f));
  float fr = (float)t * invf;
  float s = sinf(fr), c = cosf(fr);
  float* p = qk + (size_t)row * 2048;
#pragma unroll
  for (int h = 0; h < 16; ++h) {
    int c1 = h * 64 + i, c2 = c1 + 32;
    float q1 = p[c1], q2 = p[c2];
    p[c1] = (q1 * c - q2 * s) * 0.125f;
    p[c2] = (q2 * c + q1 * s) * 0.125f;
    float k1 = p[1024 + c1], k2 = p[1024 + c2];
    p[1024 + c1] = k1 * c - k2 * s;
    p[1024 + c2] = k2 * c + k1 * s;
  }
}

// ---------- Fused retention v4: 8 waves, e-strip split, grouped LDS layouts ----------
__global__ __launch_bounds__(512) void k_retention(const float* __restrict__ qk, const u16* __restrict__ vg,
                                                   const float* __restrict__ gnw, u16* __restrict__ og) {
  int bh = blockIdx.x & 63, rq = blockIdx.x >> 6;
  int h = bh & 15, b = bh >> 4;
  int gi0 = rq * 16;

  __shared__ __attribute__((aligned(16))) float qs[16][68];      // q rows [i][d]
  __shared__ __attribute__((aligned(16))) float ks[64][68];      // k row-major [j][d]
  __shared__ __attribute__((aligned(16))) float attnf[2][16][68];// qk^T kh-partials [kh][i][j]
  __shared__ __attribute__((aligned(16))) u16 vst[128][88];      // v^T [e][j]
  __shared__ __attribute__((aligned(16))) u16 kta_h[8][520];     // (kdec*k)^T hi, [j>>3][d*8+(j&7)]
  __shared__ __attribute__((aligned(16))) u16 kta_l[8][520];
  __shared__ __attribute__((aligned(16))) u16 sst_h[8][1040];    // S^T hi, [d>>3][e*8+(d&7)]
  __shared__ __attribute__((aligned(16))) u16 sst_l[8][1040];
  __shared__ float dpow[72];
  __shared__ float ssred[8][16];

  int tid = threadIdx.x;
  int w = tid >> 6, l = tid & 63;
  int fr = l & 15, fq = l >> 4;
  float gamma = 1.f - exp2f(-5.f - (float)h);
  if (tid <= 64) dpow[tid] = powf(gamma, (float)tid);
  for (int c = tid; c < 8 * 520; c += 512) { ((u32*)sst_h)[c] = 0; ((u32*)sst_l)[c] = 0; }
  __syncthreads();
  float cdec = dpow[64];

  int e0 = w * 16;
  int ct = w & 3, kha = w >> 2;
  float gww = gnw[e0 + fr];
  int khmax = (gi0 + 15 < 32) ? 1 : 2;
  bool attn_live = (16 * ct <= gi0 + 15);

  int sj = tid >> 3, sdg = (tid & 7) * 8;
  int vjp = tid & 31, ve8 = (tid >> 5) * 8;

  f32x4 Sacc[4];
#pragma unroll
  for (int dt = 0; dt < 4; ++dt) Sacc[dt] = (f32x4){0.f, 0.f, 0.f, 0.f};

  for (int n = 0; n < 32; ++n) {
    int rowbase = b * 2048 + n * 64;
    // ---- phase 1: stage q, k (+grouped kdec*k^T), v^T ----
    if (tid < 256) {
      int i = tid >> 4, d4 = (tid & 15) * 4;
      *(f32x4*)&qs[i][d4] = *(const f32x4*)&qk[(size_t)(rowbase + gi0 + i) * 2048 + h * 64 + d4];
    }
    {
      const float* kr = &qk[(size_t)(rowbase + sj) * 2048 + 1024 + h * 64 + sdg];
      f32x4 ka = *(const f32x4*)kr;
      f32x4 kb2 = *(const f32x4*)(kr + 4);
      *(f32x4*)&ks[sj][sdg] = ka;
      *(f32x4*)&ks[sj][sdg + 4] = kb2;
      float kdv = dpow[63 - sj];
      float kd[8];
#pragma unroll
      for (int m = 0; m < 4; ++m) { kd[m] = ka[m] * kdv; kd[m + 4] = kb2[m] * kdv; }
      bf16x8 kh8, kl8;
      split8r(kd, kh8, kl8);
      int g = sj >> 3, s = sj & 7;
#pragma unroll
      for (int m = 0; m < 8; ++m) {
        kta_h[g][(sdg + m) * 8 + s] = (u16)kh8[m];
        kta_l[g][(sdg + m) * 8 + s] = (u16)kl8[m];
      }
      const u16* vr = &vg[(size_t)(rowbase + 2 * vjp) * 4096 + h * 128 + ve8];
      bf16x8 va = *(const bf16x8*)vr;
      bf16x8 vb = *(const bf16x8*)(vr + 4096);
#pragma unroll
      for (int m = 0; m < 8; ++m)
        *(u32*)&vst[ve8 + m][2 * vjp] = (u32)(u16)va[m] | ((u32)(u16)vb[m] << 16);
    }
    __syncthreads();
    // ---- phase 2: attn partial (ct, kha) ----
    {
      f32x4 at = (f32x4){0.f, 0.f, 0.f, 0.f};
      if (attn_live) {
        bf16x8 qh, ql, kbh, kbl;
        split8p(&qs[fr][kha * 32 + fq * 8], qh, ql);
        split8p(&ks[16 * ct + fr][kha * 32 + fq * 8], kbh, kbl);
        at = __builtin_amdgcn_mfma_f32_16x16x32_bf16(qh, kbh, at, 0, 0, 0);
        at = __builtin_amdgcn_mfma_f32_16x16x32_bf16(qh, kbl, at, 0, 0, 0);
        at = __builtin_amdgcn_mfma_f32_16x16x32_bf16(ql, kbh, at, 0, 0, 0);
      }
#pragma unroll
      for (int r = 0; r < 4; ++r) attnf[kha][fq * 4 + r][16 * ct + fr] = at[r];
    }
    __syncthreads();
    // ---- phase 3a: o1 = attn@v, o2 = q@S for e-strip ----
    f32x4 o1 = (f32x4){0.f, 0.f, 0.f, 0.f};
    f32x4 o2 = (f32x4){0.f, 0.f, 0.f, 0.f};
#pragma unroll
    for (int kh2 = 0; kh2 < 2; ++kh2) {
      bf16x8 qh, ql;
      split8p(&qs[fr][kh2 * 32 + fq * 8], qh, ql);
      bf16x8 sh = *(const bf16x8*)&sst_h[kh2 * 4 + fq][(e0 + fr) * 8];
      bf16x8 sl = *(const bf16x8*)&sst_l[kh2 * 4 + fq][(e0 + fr) * 8];
      o2 = __builtin_amdgcn_mfma_f32_16x16x32_bf16(qh, sh, o2, 0, 0, 0);
      o2 = __builtin_amdgcn_mfma_f32_16x16x32_bf16(qh, sl, o2, 0, 0, 0);
      o2 = __builtin_amdgcn_mfma_f32_16x16x32_bf16(ql, sh, o2, 0, 0, 0);
      if (kh2 < khmax) {
        float tmp[8];
        int gi = gi0 + fr;
#pragma unroll
        for (int m = 0; m < 8; ++m) {
          int kk = kh2 * 32 + fq * 8 + m;
          float raw = attnf[0][fr][kk] + attnf[1][fr][kk];
          int s = gi - kk;
          tmp[m] = (s >= 0) ? raw * dpow[s] : 0.f;
        }
        bf16x8 ath, atl;
        split8r(tmp, ath, atl);
        bf16x8 bv = *(const bf16x8*)&vst[e0 + fr][kh2 * 32 + fq * 8];
        o1 = __builtin_amdgcn_mfma_f32_16x16x32_bf16(ath, bv, o1, 0, 0, 0);
        o1 = __builtin_amdgcn_mfma_f32_16x16x32_bf16(atl, bv, o1, 0, 0, 0);
      }
    }
    float ofin[4], ssp[4];
#pragma unroll
    for (int r = 0; r < 4; ++r) {
      int gi = gi0 + fq * 4 + r;
      ofin[r] = o1[r] + dpow[gi + 1] * o2[r];
      ssp[r] = ofin[r] * ofin[r];
    }
#pragma unroll
    for (int r = 0; r < 4; ++r) {
      ssp[r] += __shfl_xor(ssp[r], 1, 64);
      ssp[r] += __shfl_xor(ssp[r], 2, 64);
      ssp[r] += __shfl_xor(ssp[r], 4, 64);
      ssp[r] += __shfl_xor(ssp[r], 8, 64);
    }
    if (fr == 0) {
#pragma unroll
      for (int r = 0; r < 4; ++r) ssred[w][fq * 4 + r] = ssp[r];
    }
    __syncthreads();
    // ---- phase 3b: rms + gate + store; then S-update ----
#pragma unroll
    for (int r = 0; r < 4; ++r) {
      int i16 = fq * 4 + r;
      float tot = 0.f;
#pragma unroll
      for (int w2 = 0; w2 < 8; ++w2) tot += ssred[w2][i16];
      float rms = rsqrtf(tot * (1.f / 128.f) + 1e-5f);
      int grow = rowbase + gi0 + i16;
      float g = bf2f(vg[(size_t)grow * 4096 + 2048 + h * 128 + e0 + fr]);
      float y = ofin[r] * rms * gww * (g / (1.f + expf(-g)));
      og[(size_t)grow * 2048 + h * 128 + e0 + fr] = f2bf(y);
    }
    if (n < 31) {
#pragma unroll
      for (int dt = 0; dt < 4; ++dt) {
#pragma unroll
        for (int r = 0; r < 4; ++r) Sacc[dt][r] *= cdec;
      }
#pragma unroll
      for (int kh2 = 0; kh2 < 2; ++kh2) {
        bf16x8 bv = *(const bf16x8*)&vst[e0 + fr][kh2 * 32 + fq * 8];
#pragma unroll
        for (int dt = 0; dt < 4; ++dt) {
          bf16x8 ah = *(const bf16x8*)&kta_h[kh2 * 4 + fq][(dt * 16 + fr) * 8];
          bf16x8 al = *(const bf16x8*)&kta_l[kh2 * 4 + fq][(dt * 16 + fr) * 8];
          Sacc[dt] = __builtin_amdgcn_mfma_f32_16x16x32_bf16(ah, bv, Sacc[dt], 0, 0, 0);
          Sacc[dt] = __builtin_amdgcn_mfma_f32_16x16x32_bf16(al, bv, Sacc[dt], 0, 0, 0);
        }
      }
#pragma unroll
      for (int dt = 0; dt < 4; ++dt) {
        ushort4 wh, wl;
#pragma unroll
        for (int r = 0; r < 4; ++r) {
          union { float f; u32 u; } c; c.f = Sacc[dt][r];
          union { u32 u; float f; } hf; hf.u = c.u & 0xffff0000u;
          union { float f; u32 u; } lw; lw.f = Sacc[dt][r] - hf.f;
          ((u16*)&wh)[r] = (u16)(c.u >> 16);
          ((u16*)&wl)[r] = (u16)(lw.u >> 16);
        }
        int g = dt * 2 + (fq >> 1);
        int idx = (e0 + fr) * 8 + (fq & 1) * 4;
        *(ushort4*)&sst_h[g][idx] = wh;
        *(ushort4*)&sst_l[g][idx] = wl;
      }
    }
    __syncthreads();
  }
}

extern "C" void kernel_launch(void* const* d_in, const int* in_sizes, int n_in,
                              void* d_out, int out_size, void* d_ws, size_t ws_size,
                              hipStream_t stream) {
  const float* x   = (const float*)d_in[0];
  const float* Wq  = (const float*)d_in[1];
  const float* Wk  = (const float*)d_in[2];
  const float* Wv  = (const float*)d_in[3];
  const float* Wg  = (const float*)d_in[4];
  const float* Wo  = (const float*)d_in[5];
  const float* gnw = (const float*)d_in[6];
  float* out = (float*)d_out;

  const size_t MB = 1024 * 1024;
  char* ws = (char*)d_ws;
  u16*  xb   = (u16*)(ws + 0 * MB);
  u16*  Wqkb = (u16*)(ws + 16 * MB);
  u16*  Wvgb = (u16*)(ws + 20 * MB);
  float* qk  = (float*)(ws + 32 * MB);
  u16*  vg   = (u16*)(ws + 96 * MB);
  u16*  Wob  = (u16*)(ws + 160 * MB);
  u16*  og   = (u16*)(ws + 0 * MB);   // overlay (xb/Wqkb/Wvgb dead by then)
  const size_t NEED = 164 * MB;
  if (ws_size < NEED) {
    k_sentinel<<<1, 64, 0, stream>>>(out);
    return;
  }

  k_cvt_x<<<8192, 256, 0, stream>>>(x, xb);
  k_transpose<<<dim3(32, 32), 256, 0, stream>>>(Wq, Wqkb, 1024, 1024);
  k_transpose<<<dim3(32, 32), 256, 0, stream>>>(Wk, Wqkb + (size_t)1024 * 1024, 1024, 1024);
  k_transpose<<<dim3(64, 32), 256, 0, stream>>>(Wv, Wvgb, 1024, 2048);
  k_transpose<<<dim3(64, 32), 256, 0, stream>>>(Wg, Wvgb + (size_t)2048 * 1024, 1024, 2048);
  k_transpose<<<dim3(32, 64), 256, 0, stream>>>(Wo, Wob, 2048, 1024);

  k_gemm<false><<<dim3(16, 64), 256, 0, stream>>>(xb, Wqkb, qk, 2048, 1024);  // qk f32
  k_gemm<true ><<<dim3(32, 64), 256, 0, stream>>>(xb, Wvgb, vg, 4096, 1024);  // v|g bf16
  k_rope<<<1024, 256, 0, stream>>>(qk);
  k_retention<<<256, 512, 0, stream>>>(qk, vg, gnw, og);
  k_gemm<false><<<dim3(8, 64), 256, 0, stream>>>(og, Wob, out, 1024, 2048);   // out f32
}

// Round 7
// 337.928 us; speedup vs baseline: 2.0688x; 1.1702x over previous
//
#include <hip/hip_runtime.h>
#include <hip/hip_bf16.h>
#include <math.h>

typedef unsigned short u16;
typedef unsigned int u32;
typedef __attribute__((ext_vector_type(8))) short bf16x8;
typedef __attribute__((ext_vector_type(4))) float f32x4;

// B=4, T=2048, D=1024, H=16, DK=64, DV=128, CHUNK=64, N_CHUNKS=32

__device__ __forceinline__ u16 f2bf(float f) {
  union { float f; unsigned u; } a; a.f = f;
  unsigned u = a.u;
  unsigned r = (u + 0x7fffu + ((u >> 16) & 1u)) >> 16;
  return (u16)r;
}
__device__ __forceinline__ float bf2f(u16 s) {
  union { unsigned u; float f; } a; a.u = ((unsigned)s) << 16; return a.f;
}

__global__ void k_sentinel(float* out) {
  if (threadIdx.x == 0 && blockIdx.x == 0) out[0] = 1.0e6f;
}

// exact split: f32 -> bf16 hi + bf16 lo (hi+lo == f to ~2^-16 rel)
__device__ __forceinline__ void split8r(const float* t, bf16x8& hi, bf16x8& lo) {
#pragma unroll
  for (int m = 0; m < 8; ++m) {
    union { float f; u32 u; } c; c.f = t[m];
    union { u32 u; float f; } hf; hf.u = c.u & 0xffff0000u;
    union { float f; u32 u; } lw; lw.f = t[m] - hf.f;
    hi[m] = (short)(u16)(c.u >> 16);
    lo[m] = (short)(u16)(lw.u >> 16);
  }
}
__device__ __forceinline__ void split8p(const float* __restrict__ p, bf16x8& hi, bf16x8& lo) {
  f32x4 a = *(const f32x4*)p;
  f32x4 b = *(const f32x4*)(p + 4);
  float t[8];
  t[0]=a[0]; t[1]=a[1]; t[2]=a[2]; t[3]=a[3]; t[4]=b[0]; t[5]=b[1]; t[6]=b[2]; t[7]=b[3];
  split8r(t, hi, lo);
}

// async global->LDS, 16B per lane; lds base wave-uniform (HW adds lane*16)
__device__ __forceinline__ void gload16(const u16* g, u16* l) {
  __builtin_amdgcn_global_load_lds(
      (const __attribute__((address_space(1))) unsigned int*)g,
      (__attribute__((address_space(3))) unsigned int*)l, 16, 0, 0);
}

// ---------- x f32 -> bf16 ----------
__global__ __launch_bounds__(256) void k_cvt_x(const float* __restrict__ src, u16* __restrict__ dst) {
  int i = blockIdx.x * 256 + threadIdx.x;
  float4 v = ((const float4*)src)[i];
  ushort4 o;
  o.x = f2bf(v.x); o.y = f2bf(v.y); o.z = f2bf(v.z); o.w = f2bf(v.w);
  ((ushort4*)dst)[i] = o;
}

// ---------- W [K][N] f32 -> [N][K] bf16 (tiled transpose) ----------
__global__ __launch_bounds__(256) void k_transpose(const float* __restrict__ src, u16* __restrict__ dst,
                                                   int K, int N) {
  __shared__ float tile[32][33];
  int n0 = blockIdx.x * 32, k0 = blockIdx.y * 32;
  int tx = threadIdx.x & 31, ty = threadIdx.x >> 5;
  for (int r = 0; r < 32; r += 8)
    tile[ty + r][tx] = src[(size_t)(k0 + ty + r) * N + n0 + tx];
  __syncthreads();
  for (int r = 0; r < 32; r += 8)
    dst[(size_t)(n0 + ty + r) * K + k0 + tx] = f2bf(tile[tx][ty + r]);
}

// ---------- bf16 GEMM via global_load_lds (round-6 proven) ----------
template <bool BF16OUT>
__global__ __launch_bounds__(256, 2) void k_gemm(const u16* __restrict__ A, const u16* __restrict__ Bt,
                                                 void* __restrict__ Cv, int N, int K) {
  __shared__ __attribute__((aligned(16))) u16 As[128 * 32];
  __shared__ __attribute__((aligned(16))) u16 Bs[128 * 32];
  int nbx = gridDim.x;
  int id = blockIdx.y * nbx + blockIdx.x;
  int cpx = (nbx * gridDim.y) >> 3;
  int sw = (id & 7) * cpx + (id >> 3);
  int bx = sw % nbx, by = sw / nbx;
  int i0 = by * 128, n0 = bx * 128;
  int tid = threadIdx.x;
  int lane = tid & 63, w = tid >> 6;
  int wr = (w >> 1) * 64, wc = (w & 1) * 64;
  int srow = lane >> 2, scol = (lane & 3) * 8;
  f32x4 acc[4][4];
#pragma unroll
  for (int m = 0; m < 4; ++m)
#pragma unroll
    for (int n = 0; n < 4; ++n) acc[m][n] = (f32x4){0.f, 0.f, 0.f, 0.f};
  int fr = lane & 15, kb = (lane >> 4) * 8;
  for (int k0 = 0; k0 < K; k0 += 32) {
    __syncthreads();
#pragma unroll
    for (int q = 0; q < 2; ++q) {
      int s = w * 2 + q;
      gload16(&A[(size_t)(i0 + s * 16 + srow) * K + k0 + scol], &As[s * 512]);
      gload16(&Bt[(size_t)(n0 + s * 16 + srow) * K + k0 + scol], &Bs[s * 512]);
    }
    asm volatile("s_waitcnt vmcnt(0)" ::: "memory");
    __syncthreads();
    bf16x8 af[4], bfr[4];
#pragma unroll
    for (int m = 0; m < 4; ++m) af[m] = *(const bf16x8*)&As[(wr + m * 16 + fr) * 32 + kb];
#pragma unroll
    for (int n = 0; n < 4; ++n) bfr[n] = *(const bf16x8*)&Bs[(wc + n * 16 + fr) * 32 + kb];
#pragma unroll
    for (int m = 0; m < 4; ++m)
#pragma unroll
      for (int n = 0; n < 4; ++n)
        acc[m][n] = __builtin_amdgcn_mfma_f32_16x16x32_bf16(af[m], bfr[n], acc[m][n], 0, 0, 0);
  }
  int rb = (lane >> 4) * 4, cb = lane & 15;
#pragma unroll
  for (int m = 0; m < 4; ++m)
#pragma unroll
    for (int n = 0; n < 4; ++n) {
      int gr = i0 + wr + m * 16 + rb;
      int gc = n0 + wc + n * 16 + cb;
#pragma unroll
      for (int r = 0; r < 4; ++r) {
        float v = acc[m][n][r];
        if (BF16OUT) ((u16*)Cv)[(size_t)(gr + r) * N + gc] = f2bf(v);
        else         ((float*)Cv)[(size_t)(gr + r) * N + gc] = v;
      }
    }
}

// ---------- RoPE in place ----------
__global__ __launch_bounds__(256) void k_rope(float* __restrict__ qk) {
  int idx = blockIdx.x * 256 + threadIdx.x;
  int i = idx & 31;
  int row = idx >> 5;
  int t = row & 2047;
  float invf = powf(10000.f, -(float)i * (1.f / 32.f));
  float fr = (float)t * invf;
  float s = sinf(fr), c = cosf(fr);
  float* p = qk + (size_t)row * 2048;
#pragma unroll
  for (int h = 0; h < 16; ++h) {
    int c1 = h * 64 + i, c2 = c1 + 32;
    float q1 = p[c1], q2 = p[c2];
    p[c1] = (q1 * c - q2 * s) * 0.125f;
    p[c2] = (q2 * c + q1 * s) * 0.125f;
    float k1 = p[1024 + c1], k2 = p[1024 + c2];
    p[1024 + c1] = k1 * c - k2 * s;
    p[1024 + c2] = k2 * c + k1 * s;
  }
}

// ---------- Fused retention v5: wave-specialized, no attnf round-trip ----------
// 256 blocks = (rq 4) x (bh 64). 8 waves: phase2 = {waves 0-3: full-K attn tile ->
// decayed bf16 hi/lo grouped pa} || {waves 4-7: S-update MFMAs -> sst[next]}.
// kta uses XOR block swizzle blk'=d^((d>>3)&7): producer stores 2-way, reads uniform.
__global__ __launch_bounds__(512) void k_retention(const float* __restrict__ qk, const u16* __restrict__ vg,
                                                   const float* __restrict__ gnw, u16* __restrict__ og) {
  int bh = blockIdx.x & 63, rq = blockIdx.x >> 6;
  int h = bh & 15, b = bh >> 4;
  int gi0 = rq * 16;

  __shared__ __attribute__((aligned(16))) float qs[16][68];      // q rows [i][d]
  __shared__ __attribute__((aligned(16))) float ks[64][68];      // k row-major [j][d]
  __shared__ __attribute__((aligned(16))) u16 vst[128][88];      // v^T [e][j]
  __shared__ __attribute__((aligned(16))) u16 kta_h[8][520];     // (kdec*k)^T hi, [j>>3][blk'(d)*8+(j&7)]
  __shared__ __attribute__((aligned(16))) u16 kta_l[8][520];
  __shared__ __attribute__((aligned(16))) u16 pa_h[8][136];      // decayed attn hi, [j>>3][i*8+(j&7)]
  __shared__ __attribute__((aligned(16))) u16 pa_l[8][136];
  __shared__ __attribute__((aligned(16))) u16 sst_h[2][8][1040]; // S^T hi, dbuf, [d>>3][e*8+(d&7)]
  __shared__ __attribute__((aligned(16))) u16 sst_l[2][8][1040];
  __shared__ float dpow[72];
  __shared__ float ssred[8][16];

  int tid = threadIdx.x;
  int w = tid >> 6, l = tid & 63;
  int fr = l & 15, fq = l >> 4;
  float gamma = 1.f - exp2f(-5.f - (float)h);
  if (tid <= 64) dpow[tid] = powf(gamma, (float)tid);
  for (int c = tid; c < 4160; c += 512) { ((u32*)sst_h[0])[c] = 0; ((u32*)sst_l[0])[c] = 0; }
  __syncthreads();
  float cdec = dpow[64];

  int e0 = w * 16;
  float gww = gnw[e0 + fr];
  int khmax = (rq < 2) ? 1 : 2;

  // staging roles
  int sj = tid >> 3, sdg = (tid & 7) * 8;        // k: row sj, d-octet sdg
  int vjp = tid & 31, ve8 = (tid >> 5) * 8;      // v^T paired-u32

  f32x4 Sacc[4][2];                              // waves 4-7: d-tile x e-subtile (eb=32*(w-4))
#pragma unroll
  for (int dt = 0; dt < 4; ++dt)
#pragma unroll
    for (int nt = 0; nt < 2; ++nt) Sacc[dt][nt] = (f32x4){0.f, 0.f, 0.f, 0.f};

  for (int n = 0; n < 32; ++n) {
    int rowbase = b * 2048 + n * 64;
    int cur = n & 1;
    // ---- phase 1: stage q, k row-major, kta (swizzled), v^T ----
    if (tid < 256) {
      int i = tid >> 4, d4 = (tid & 15) * 4;
      *(f32x4*)&qs[i][d4] = *(const f32x4*)&qk[(size_t)(rowbase + gi0 + i) * 2048 + h * 64 + d4];
    }
    {
      const float* kr = &qk[(size_t)(rowbase + sj) * 2048 + 1024 + h * 64 + sdg];
      f32x4 ka = *(const f32x4*)kr;
      f32x4 kb2 = *(const f32x4*)(kr + 4);
      *(f32x4*)&ks[sj][sdg] = ka;
      *(f32x4*)&ks[sj][sdg + 4] = kb2;
      float kdv = dpow[63 - sj];
      float kd[8];
#pragma unroll
      for (int m = 0; m < 4; ++m) { kd[m] = ka[m] * kdv; kd[m + 4] = kb2[m] * kdv; }
      bf16x8 kh8, kl8;
      split8r(kd, kh8, kl8);
      int J = sj >> 3, s = sj & 7, dh = tid & 7;   // d = dh*8+m; blk' = d ^ dh
#pragma unroll
      for (int m = 0; m < 8; ++m) {
        int blk = (dh * 8) | (m ^ dh);
        kta_h[J][blk * 8 + s] = (u16)kh8[m];
        kta_l[J][blk * 8 + s] = (u16)kl8[m];
      }
      const u16* vr = &vg[(size_t)(rowbase + 2 * vjp) * 4096 + h * 128 + ve8];
      bf16x8 va = *(const bf16x8*)vr;
      bf16x8 vb = *(const bf16x8*)(vr + 4096);
#pragma unroll
      for (int m = 0; m < 8; ++m)
        *(u32*)&vst[ve8 + m][2 * vjp] = (u32)(u16)va[m] | ((u32)(u16)vb[m] << 16);
    }
    __syncthreads();
    // ---- phase 2: waves 0-3 attn -> pa ; waves 4-7 S-update -> sst[cur^1] ----
    if (w < 4) {
      int ct = w;
      f32x4 at = (f32x4){0.f, 0.f, 0.f, 0.f};
      if (16 * ct <= gi0 + 15) {
#pragma unroll
        for (int kh = 0; kh < 2; ++kh) {
          bf16x8 qh, ql, kbh, kbl;
          split8p(&qs[fr][kh * 32 + fq * 8], qh, ql);
          split8p(&ks[16 * ct + fr][kh * 32 + fq * 8], kbh, kbl);
          at = __builtin_amdgcn_mfma_f32_16x16x32_bf16(qh, kbh, at, 0, 0, 0);
          at = __builtin_amdgcn_mfma_f32_16x16x32_bf16(qh, kbl, at, 0, 0, 0);
          at = __builtin_amdgcn_mfma_f32_16x16x32_bf16(ql, kbh, at, 0, 0, 0);
        }
      }
      int j = 16 * ct + fr;
      int J = j >> 3, jc = j & 7;
#pragma unroll
      for (int r = 0; r < 4; ++r) {
        int i = fq * 4 + r, s = gi0 + i - j;
        float val = (s >= 0) ? at[r] * dpow[s] : 0.f;
        union { float f; u32 u; } c; c.f = val;
        union { u32 u; float f; } hf; hf.u = c.u & 0xffff0000u;
        union { float f; u32 u; } lw; lw.f = val - hf.f;
        pa_h[J][i * 8 + jc] = (u16)(c.u >> 16);
        pa_l[J][i * 8 + jc] = (u16)(lw.u >> 16);
      }
    } else if (n < 31) {
      int eb = (w - 4) * 32;
#pragma unroll
      for (int dt = 0; dt < 4; ++dt)
#pragma unroll
        for (int nt = 0; nt < 2; ++nt)
#pragma unroll
          for (int r = 0; r < 4; ++r) Sacc[dt][nt][r] *= cdec;
      bf16x8 bv[2][2];
#pragma unroll
      for (int kh2 = 0; kh2 < 2; ++kh2)
#pragma unroll
        for (int nt = 0; nt < 2; ++nt)
          bv[kh2][nt] = *(const bf16x8*)&vst[eb + nt * 16 + fr][kh2 * 32 + fq * 8];
#pragma unroll
      for (int kh2 = 0; kh2 < 2; ++kh2) {
#pragma unroll
        for (int dt = 0; dt < 4; ++dt) {
          int d = dt * 16 + fr;
          int blk = d ^ ((dt * 2 + (fr >> 3)) & 7);
          bf16x8 ah = *(const bf16x8*)&kta_h[kh2 * 4 + fq][blk * 8];
          bf16x8 al = *(const bf16x8*)&kta_l[kh2 * 4 + fq][blk * 8];
#pragma unroll
          for (int nt = 0; nt < 2; ++nt) {
            Sacc[dt][nt] = __builtin_amdgcn_mfma_f32_16x16x32_bf16(ah, bv[kh2][nt], Sacc[dt][nt], 0, 0, 0);
            Sacc[dt][nt] = __builtin_amdgcn_mfma_f32_16x16x32_bf16(al, bv[kh2][nt], Sacc[dt][nt], 0, 0, 0);
          }
        }
      }
      int nxt = cur ^ 1;
#pragma unroll
      for (int dt = 0; dt < 4; ++dt) {
        int g = dt * 2 + (fq >> 1);
#pragma unroll
        for (int nt = 0; nt < 2; ++nt) {
          int e = eb + nt * 16 + fr;
          ushort4 wh, wl;
#pragma unroll
          for (int r = 0; r < 4; ++r) {
            union { float f; u32 u; } c; c.f = Sacc[dt][nt][r];
            union { u32 u; float f; } hf; hf.u = c.u & 0xffff0000u;
            union { float f; u32 u; } lw; lw.f = Sacc[dt][nt][r] - hf.f;
            ((u16*)&wh)[r] = (u16)(c.u >> 16);
            ((u16*)&wl)[r] = (u16)(lw.u >> 16);
          }
          int idx = e * 8 + (fq & 1) * 4;
          *(ushort4*)&sst_h[nxt][g][idx] = wh;
          *(ushort4*)&sst_l[nxt][g][idx] = wl;
        }
      }
    }
    __syncthreads();
    // ---- phase 3: o1 = pa@v, o2 = q@S for e-strip e0..e0+16 ----
    f32x4 o1 = (f32x4){0.f, 0.f, 0.f, 0.f};
    f32x4 o2 = (f32x4){0.f, 0.f, 0.f, 0.f};
#pragma unroll
    for (int kh2 = 0; kh2 < 2; ++kh2) {
      bf16x8 qh, ql;
      split8p(&qs[fr][kh2 * 32 + fq * 8], qh, ql);
      bf16x8 sh = *(const bf16x8*)&sst_h[cur][kh2 * 4 + fq][(e0 + fr) * 8];
      bf16x8 sl = *(const bf16x8*)&sst_l[cur][kh2 * 4 + fq][(e0 + fr) * 8];
      o2 = __builtin_amdgcn_mfma_f32_16x16x32_bf16(qh, sh, o2, 0, 0, 0);
      o2 = __builtin_amdgcn_mfma_f32_16x16x32_bf16(qh, sl, o2, 0, 0, 0);
      o2 = __builtin_amdgcn_mfma_f32_16x16x32_bf16(ql, sh, o2, 0, 0, 0);
      if (kh2 < khmax) {
        bf16x8 ph = *(const bf16x8*)&pa_h[kh2 * 4 + fq][fr * 8];
        bf16x8 pl = *(const bf16x8*)&pa_l[kh2 * 4 + fq][fr * 8];
        bf16x8 bvv = *(const bf16x8*)&vst[e0 + fr][kh2 * 32 + fq * 8];
        o1 = __builtin_amdgcn_mfma_f32_16x16x32_bf16(ph, bvv, o1, 0, 0, 0);
        o1 = __builtin_amdgcn_mfma_f32_16x16x32_bf16(pl, bvv, o1, 0, 0, 0);
      }
    }
    float ofin[4], ssp[4];
#pragma unroll
    for (int r = 0; r < 4; ++r) {
      int gi = gi0 + fq * 4 + r;
      ofin[r] = o1[r] + dpow[gi + 1] * o2[r];
      ssp[r] = ofin[r] * ofin[r];
    }
#pragma unroll
    for (int r = 0; r < 4; ++r) {
      ssp[r] += __shfl_xor(ssp[r], 1, 64);
      ssp[r] += __shfl_xor(ssp[r], 2, 64);
      ssp[r] += __shfl_xor(ssp[r], 4, 64);
      ssp[r] += __shfl_xor(ssp[r], 8, 64);
    }
    if (fr == 0) {
#pragma unroll
      for (int r = 0; r < 4; ++r) ssred[w][fq * 4 + r] = ssp[r];
    }
    __syncthreads();
    // ---- phase 4: rms + gate + store og ----
#pragma unroll
    for (int r = 0; r < 4; ++r) {
      int i16 = fq * 4 + r;
      float tot = 0.f;
#pragma unroll
      for (int w2 = 0; w2 < 8; ++w2) tot += ssred[w2][i16];
      float rms = rsqrtf(tot * (1.f / 128.f) + 1e-5f);
      int grow = rowbase + gi0 + i16;
      float g = bf2f(vg[(size_t)grow * 4096 + 2048 + h * 128 + e0 + fr]);
      float y = ofin[r] * rms * gww * (g / (1.f + expf(-g)));
      og[(size_t)grow * 2048 + h * 128 + e0 + fr] = f2bf(y);
    }
  }
}

extern "C" void kernel_launch(void* const* d_in, const int* in_sizes, int n_in,
                              void* d_out, int out_size, void* d_ws, size_t ws_size,
                              hipStream_t stream) {
  const float* x   = (const float*)d_in[0];
  const float* Wq  = (const float*)d_in[1];
  const float* Wk  = (const float*)d_in[2];
  const float* Wv  = (const float*)d_in[3];
  const float* Wg  = (const float*)d_in[4];
  const float* Wo  = (const float*)d_in[5];
  const float* gnw = (const float*)d_in[6];
  float* out = (float*)d_out;

  const size_t MB = 1024 * 1024;
  char* ws = (char*)d_ws;
  u16*  xb   = (u16*)(ws + 0 * MB);
  u16*  Wqkb = (u16*)(ws + 16 * MB);
  u16*  Wvgb = (u16*)(ws + 20 * MB);
  float* qk  = (float*)(ws + 32 * MB);
  u16*  vg   = (u16*)(ws + 96 * MB);
  u16*  Wob  = (u16*)(ws + 160 * MB);
  u16*  og   = (u16*)(ws + 0 * MB);   // overlay (xb/Wqkb/Wvgb dead by then)
  const size_t NEED = 164 * MB;
  if (ws_size < NEED) {
    k_sentinel<<<1, 64, 0, stream>>>(out);
    return;
  }

  k_cvt_x<<<8192, 256, 0, stream>>>(x, xb);
  k_transpose<<<dim3(32, 32), 256, 0, stream>>>(Wq, Wqkb, 1024, 1024);
  k_transpose<<<dim3(32, 32), 256, 0, stream>>>(Wk, Wqkb + (size_t)1024 * 1024, 1024, 1024);
  k_transpose<<<dim3(64, 32), 256, 0, stream>>>(Wv, Wvgb, 1024, 2048);
  k_transpose<<<dim3(64, 32), 256, 0, stream>>>(Wg, Wvgb + (size_t)2048 * 1024, 1024, 2048);
  k_transpose<<<dim3(32, 64), 256, 0, stream>>>(Wo, Wob, 2048, 1024);

  k_gemm<false><<<dim3(16, 64), 256, 0, stream>>>(xb, Wqkb, qk, 2048, 1024);  // qk f32
  k_gemm<true ><<<dim3(32, 64), 256, 0, stream>>>(xb, Wvgb, vg, 4096, 1024);  // v|g bf16
  k_rope<<<1024, 256, 0, stream>>>(qk);
  k_retention<<<256, 512, 0, stream>>>(qk, vg, gnw, og);
  k_gemm<false><<<dim3(8, 64), 256, 0, stream>>>(og, Wob, out, 1024, 2048);   // out f32
}

// Round 8
// 330.358 us; speedup vs baseline: 2.1162x; 1.0229x over previous
//
#include <hip/hip_runtime.h>
#include <hip/hip_bf16.h>
#include <math.h>

typedef unsigned short u16;
typedef unsigned int u32;
typedef __attribute__((ext_vector_type(8))) short bf16x8;
typedef __attribute__((ext_vector_type(4))) float f32x4;

// B=4, T=2048, D=1024, H=16, DK=64, DV=128, CHUNK=64, N_CHUNKS=32

__device__ __forceinline__ u16 f2bf(float f) {
  union { float f; unsigned u; } a; a.f = f;
  unsigned u = a.u;
  unsigned r = (u + 0x7fffu + ((u >> 16) & 1u)) >> 16;
  return (u16)r;
}
__device__ __forceinline__ float bf2f(u16 s) {
  union { unsigned u; float f; } a; a.u = ((unsigned)s) << 16; return a.f;
}

__global__ void k_sentinel(float* out) {
  if (threadIdx.x == 0 && blockIdx.x == 0) out[0] = 1.0e6f;
}

// exact split: f32 -> bf16 hi + bf16 lo (hi+lo == f to ~2^-16 rel)
__device__ __forceinline__ void split8r(const float* t, bf16x8& hi, bf16x8& lo) {
#pragma unroll
  for (int m = 0; m < 8; ++m) {
    union { float f; u32 u; } c; c.f = t[m];
    union { u32 u; float f; } hf; hf.u = c.u & 0xffff0000u;
    union { float f; u32 u; } lw; lw.f = t[m] - hf.f;
    hi[m] = (short)(u16)(c.u >> 16);
    lo[m] = (short)(u16)(lw.u >> 16);
  }
}
__device__ __forceinline__ void split8p(const float* __restrict__ p, bf16x8& hi, bf16x8& lo) {
  f32x4 a = *(const f32x4*)p;
  f32x4 b = *(const f32x4*)(p + 4);
  float t[8];
  t[0]=a[0]; t[1]=a[1]; t[2]=a[2]; t[3]=a[3]; t[4]=b[0]; t[5]=b[1]; t[6]=b[2]; t[7]=b[3];
  split8r(t, hi, lo);
}

// raw barrier that does NOT drain vmcnt (keeps reg-prefetch loads in flight);
// lgkmcnt(0) first so producer LDS writes are visible across the barrier.
__device__ __forceinline__ void bar_lds() {
  asm volatile("s_waitcnt lgkmcnt(0)" ::: "memory");
  __builtin_amdgcn_sched_barrier(0);
  __builtin_amdgcn_s_barrier();
}

// async global->LDS, 16B per lane; lds base wave-uniform (HW adds lane*16)
__device__ __forceinline__ void gload16(const u16* g, u16* l) {
  __builtin_amdgcn_global_load_lds(
      (const __attribute__((address_space(1))) unsigned int*)g,
      (__attribute__((address_space(3))) unsigned int*)l, 16, 0, 0);
}

// ---------- x f32 -> bf16 ----------
__global__ __launch_bounds__(256) void k_cvt_x(const float* __restrict__ src, u16* __restrict__ dst) {
  int i = blockIdx.x * 256 + threadIdx.x;
  float4 v = ((const float4*)src)[i];
  ushort4 o;
  o.x = f2bf(v.x); o.y = f2bf(v.y); o.z = f2bf(v.z); o.w = f2bf(v.w);
  ((ushort4*)dst)[i] = o;
}

// ---------- W [K][N] f32 -> [N][K] bf16 (tiled transpose) ----------
__global__ __launch_bounds__(256) void k_transpose(const float* __restrict__ src, u16* __restrict__ dst,
                                                   int K, int N) {
  __shared__ float tile[32][33];
  int n0 = blockIdx.x * 32, k0 = blockIdx.y * 32;
  int tx = threadIdx.x & 31, ty = threadIdx.x >> 5;
  for (int r = 0; r < 32; r += 8)
    tile[ty + r][tx] = src[(size_t)(k0 + ty + r) * N + n0 + tx];
  __syncthreads();
  for (int r = 0; r < 32; r += 8)
    dst[(size_t)(n0 + ty + r) * K + k0 + tx] = f2bf(tile[tx][ty + r]);
}

// ---------- bf16 GEMM via global_load_lds (round-6 proven) ----------
template <bool BF16OUT>
__global__ __launch_bounds__(256, 2) void k_gemm(const u16* __restrict__ A, const u16* __restrict__ Bt,
                                                 void* __restrict__ Cv, int N, int K) {
  __shared__ __attribute__((aligned(16))) u16 As[128 * 32];
  __shared__ __attribute__((aligned(16))) u16 Bs[128 * 32];
  int nbx = gridDim.x;
  int id = blockIdx.y * nbx + blockIdx.x;
  int cpx = (nbx * gridDim.y) >> 3;
  int sw = (id & 7) * cpx + (id >> 3);
  int bx = sw % nbx, by = sw / nbx;
  int i0 = by * 128, n0 = bx * 128;
  int tid = threadIdx.x;
  int lane = tid & 63, w = tid >> 6;
  int wr = (w >> 1) * 64, wc = (w & 1) * 64;
  int srow = lane >> 2, scol = (lane & 3) * 8;
  f32x4 acc[4][4];
#pragma unroll
  for (int m = 0; m < 4; ++m)
#pragma unroll
    for (int n = 0; n < 4; ++n) acc[m][n] = (f32x4){0.f, 0.f, 0.f, 0.f};
  int fr = lane & 15, kb = (lane >> 4) * 8;
  for (int k0 = 0; k0 < K; k0 += 32) {
    __syncthreads();
#pragma unroll
    for (int q = 0; q < 2; ++q) {
      int s = w * 2 + q;
      gload16(&A[(size_t)(i0 + s * 16 + srow) * K + k0 + scol], &As[s * 512]);
      gload16(&Bt[(size_t)(n0 + s * 16 + srow) * K + k0 + scol], &Bs[s * 512]);
    }
    asm volatile("s_waitcnt vmcnt(0)" ::: "memory");
    __syncthreads();
    bf16x8 af[4], bfr[4];
#pragma unroll
    for (int m = 0; m < 4; ++m) af[m] = *(const bf16x8*)&As[(wr + m * 16 + fr) * 32 + kb];
#pragma unroll
    for (int n = 0; n < 4; ++n) bfr[n] = *(const bf16x8*)&Bs[(wc + n * 16 + fr) * 32 + kb];
#pragma unroll
    for (int m = 0; m < 4; ++m)
#pragma unroll
      for (int n = 0; n < 4; ++n)
        acc[m][n] = __builtin_amdgcn_mfma_f32_16x16x32_bf16(af[m], bfr[n], acc[m][n], 0, 0, 0);
  }
  int rb = (lane >> 4) * 4, cb = lane & 15;
#pragma unroll
  for (int m = 0; m < 4; ++m)
#pragma unroll
    for (int n = 0; n < 4; ++n) {
      int gr = i0 + wr + m * 16 + rb;
      int gc = n0 + wc + n * 16 + cb;
#pragma unroll
      for (int r = 0; r < 4; ++r) {
        float v = acc[m][n][r];
        if (BF16OUT) ((u16*)Cv)[(size_t)(gr + r) * N + gc] = f2bf(v);
        else         ((float*)Cv)[(size_t)(gr + r) * N + gc] = v;
      }
    }
}

// ---------- RoPE in place ----------
__global__ __launch_bounds__(256) void k_rope(float* __restrict__ qk) {
  int idx = blockIdx.x * 256 + threadIdx.x;
  int i = idx & 31;
  int row = idx >> 5;
  int t = row & 2047;
  float invf = powf(10000.f, -(float)i * (1.f / 32.f));
  float fr = (float)t * invf;
  float s = sinf(fr), c = cosf(fr);
  float* p = qk + (size_t)row * 2048;
#pragma unroll
  for (int h = 0; h < 16; ++h) {
    int c1 = h * 64 + i, c2 = c1 + 32;
    float q1 = p[c1], q2 = p[c2];
    p[c1] = (q1 * c - q2 * s) * 0.125f;
    p[c2] = (q2 * c + q1 * s) * 0.125f;
    float k1 = p[1024 + c1], k2 = p[1024 + c2];
    p[1024 + c1] = k1 * c - k2 * s;
    p[1024 + c2] = k2 * c + k1 * s;
  }
}

// ---------- Fused retention v6: v5 + T14 reg-prefetch pipeline + single sst ----------
// 256 blocks = (rq 4) x (bh 64). Per chunk: {regs->LDS, syncthreads, issue next
// chunk's global loads} then compute phases separated by raw lgkmcnt-barriers
// (vmcnt stays outstanding -> HBM latency hidden under phases 2-4).
// sst single-buffered: S-update MFMAs in phase 2 (regs), sst write in phase 4
// (after phase-3's o2 reads), visible to next chunk's phase 3 via loop-top barrier.
__global__ __launch_bounds__(512) void k_retention(const float* __restrict__ qk, const u16* __restrict__ vg,
                                                   const float* __restrict__ gnw, u16* __restrict__ og) {
  int bh = blockIdx.x & 63, rq = blockIdx.x >> 6;
  int h = bh & 15, b = bh >> 4;
  int gi0 = rq * 16;

  __shared__ __attribute__((aligned(16))) float qs[16][68];      // q rows [i][d]
  __shared__ __attribute__((aligned(16))) float ks[64][68];      // k row-major [j][d]
  __shared__ __attribute__((aligned(16))) u16 vst[128][88];      // v^T [e][j]
  __shared__ __attribute__((aligned(16))) u16 kta_h[8][520];     // (kdec*k)^T hi, [j>>3][blk'(d)*8+(j&7)]
  __shared__ __attribute__((aligned(16))) u16 kta_l[8][520];
  __shared__ __attribute__((aligned(16))) u16 pa_h[8][136];      // decayed attn hi, [j>>3][i*8+(j&7)]
  __shared__ __attribute__((aligned(16))) u16 pa_l[8][136];
  __shared__ __attribute__((aligned(16))) u16 sst_h[8][1040];    // S^T hi [d>>3][e*8+(d&7)] (single buf)
  __shared__ __attribute__((aligned(16))) u16 sst_l[8][1040];
  __shared__ float dpow[72];
  __shared__ float ssred[8][16];

  int tid = threadIdx.x;
  int w = tid >> 6, l = tid & 63;
  int fr = l & 15, fq = l >> 4;
  float gamma = 1.f - exp2f(-5.f - (float)h);
  if (tid <= 64) dpow[tid] = powf(gamma, (float)tid);
  for (int c = tid; c < 4160; c += 512) { ((u32*)sst_h)[c] = 0; ((u32*)sst_l)[c] = 0; }
  __syncthreads();
  float cdec = dpow[64];

  int e0 = w * 16;
  float gww = gnw[e0 + fr];
  int khmax = (rq < 2) ? 1 : 2;

  // staging roles
  int qi = tid >> 4, qd4 = (tid & 15) * 4;       // q (tid<256)
  int sj = tid >> 3, sdg = (tid & 7) * 8;        // k: row sj, d-octet sdg
  int vjp = tid & 31, ve8 = (tid >> 5) * 8;      // v^T paired-u32

  f32x4 Sacc[4][2];                              // waves 4-7: d-tile x e-subtile (eb=32*(w-4))
#pragma unroll
  for (int dt = 0; dt < 4; ++dt)
#pragma unroll
    for (int nt = 0; nt < 2; ++nt) Sacc[dt][nt] = (f32x4){0.f, 0.f, 0.f, 0.f};

  // ---- prologue: prefetch chunk 0 into registers ----
  f32x4 pq = (f32x4){0.f, 0.f, 0.f, 0.f};
  f32x4 pk0, pk1;
  bf16x8 pva, pvb;
  {
    int rowbase = b * 2048;
    if (tid < 256) pq = *(const f32x4*)&qk[(size_t)(rowbase + gi0 + qi) * 2048 + h * 64 + qd4];
    const float* kr = &qk[(size_t)(rowbase + sj) * 2048 + 1024 + h * 64 + sdg];
    pk0 = *(const f32x4*)kr;
    pk1 = *(const f32x4*)(kr + 4);
    const u16* vr = &vg[(size_t)(rowbase + 2 * vjp) * 4096 + h * 128 + ve8];
    pva = *(const bf16x8*)vr;
    pvb = *(const bf16x8*)(vr + 4096);
  }

  for (int n = 0; n < 32; ++n) {
    int rowbase = b * 2048 + n * 64;
    // ---- phase 1b: registers -> LDS ----
    if (tid < 256) *(f32x4*)&qs[qi][qd4] = pq;
    {
      *(f32x4*)&ks[sj][sdg] = pk0;
      *(f32x4*)&ks[sj][sdg + 4] = pk1;
      float kdv = dpow[63 - sj];
      float kd[8];
#pragma unroll
      for (int m = 0; m < 4; ++m) { kd[m] = pk0[m] * kdv; kd[m + 4] = pk1[m] * kdv; }
      bf16x8 kh8, kl8;
      split8r(kd, kh8, kl8);
      int J = sj >> 3, s = sj & 7, dh = tid & 7;   // d = dh*8+m; blk' = d ^ dh
#pragma unroll
      for (int m = 0; m < 8; ++m) {
        int blk = (dh * 8) | (m ^ dh);
        kta_h[J][blk * 8 + s] = (u16)kh8[m];
        kta_l[J][blk * 8 + s] = (u16)kl8[m];
      }
#pragma unroll
      for (int m = 0; m < 8; ++m)
        *(u32*)&vst[ve8 + m][2 * vjp] = (u32)(u16)pva[m] | ((u32)(u16)pvb[m] << 16);
    }
    __syncthreads();                              // [A] full barrier (nothing in flight)
    // ---- issue prefetch for chunk n+1 (stays outstanding through phases 2-4) ----
    if (n < 31) {
      int rb2 = rowbase + 64;
      if (tid < 256) pq = *(const f32x4*)&qk[(size_t)(rb2 + gi0 + qi) * 2048 + h * 64 + qd4];
      const float* kr = &qk[(size_t)(rb2 + sj) * 2048 + 1024 + h * 64 + sdg];
      pk0 = *(const f32x4*)kr;
      pk1 = *(const f32x4*)(kr + 4);
      const u16* vr = &vg[(size_t)(rb2 + 2 * vjp) * 4096 + h * 128 + ve8];
      pva = *(const bf16x8*)vr;
      pvb = *(const bf16x8*)(vr + 4096);
    }
    // ---- phase 2: waves 0-3 attn -> pa ; waves 4-7 S-update MFMAs (regs only) ----
    if (w < 4) {
      int ct = w;
      f32x4 at = (f32x4){0.f, 0.f, 0.f, 0.f};
      if (16 * ct <= gi0 + 15) {
#pragma unroll
        for (int kh = 0; kh < 2; ++kh) {
          bf16x8 qh, ql, kbh, kbl;
          split8p(&qs[fr][kh * 32 + fq * 8], qh, ql);
          split8p(&ks[16 * ct + fr][kh * 32 + fq * 8], kbh, kbl);
          at = __builtin_amdgcn_mfma_f32_16x16x32_bf16(qh, kbh, at, 0, 0, 0);
          at = __builtin_amdgcn_mfma_f32_16x16x32_bf16(qh, kbl, at, 0, 0, 0);
          at = __builtin_amdgcn_mfma_f32_16x16x32_bf16(ql, kbh, at, 0, 0, 0);
        }
      }
      int j = 16 * ct + fr;
      int J = j >> 3, jc = j & 7;
#pragma unroll
      for (int r = 0; r < 4; ++r) {
        int i = fq * 4 + r, s = gi0 + i - j;
        float val = (s >= 0) ? at[r] * dpow[s] : 0.f;
        union { float f; u32 u; } c; c.f = val;
        union { u32 u; float f; } hf; hf.u = c.u & 0xffff0000u;
        union { float f; u32 u; } lw; lw.f = val - hf.f;
        pa_h[J][i * 8 + jc] = (u16)(c.u >> 16);
        pa_l[J][i * 8 + jc] = (u16)(lw.u >> 16);
      }
    } else if (n < 31) {
      int eb = (w - 4) * 32;
#pragma unroll
      for (int dt = 0; dt < 4; ++dt)
#pragma unroll
        for (int nt = 0; nt < 2; ++nt)
#pragma unroll
          for (int r = 0; r < 4; ++r) Sacc[dt][nt][r] *= cdec;
      bf16x8 bv[2][2];
#pragma unroll
      for (int kh2 = 0; kh2 < 2; ++kh2)
#pragma unroll
        for (int nt = 0; nt < 2; ++nt)
          bv[kh2][nt] = *(const bf16x8*)&vst[eb + nt * 16 + fr][kh2 * 32 + fq * 8];
#pragma unroll
      for (int kh2 = 0; kh2 < 2; ++kh2) {
#pragma unroll
        for (int dt = 0; dt < 4; ++dt) {
          int d = dt * 16 + fr;
          int blk = d ^ ((dt * 2 + (fr >> 3)) & 7);
          bf16x8 ah = *(const bf16x8*)&kta_h[kh2 * 4 + fq][blk * 8];
          bf16x8 al = *(const bf16x8*)&kta_l[kh2 * 4 + fq][blk * 8];
#pragma unroll
          for (int nt = 0; nt < 2; ++nt) {
            Sacc[dt][nt] = __builtin_amdgcn_mfma_f32_16x16x32_bf16(ah, bv[kh2][nt], Sacc[dt][nt], 0, 0, 0);
            Sacc[dt][nt] = __builtin_amdgcn_mfma_f32_16x16x32_bf16(al, bv[kh2][nt], Sacc[dt][nt], 0, 0, 0);
          }
        }
      }
    }
    bar_lds();                                    // [B] keeps prefetch in flight
    // ---- phase 3: o1 = pa@v, o2 = q@S(old) for e-strip e0..e0+16 ----
    f32x4 o1 = (f32x4){0.f, 0.f, 0.f, 0.f};
    f32x4 o2 = (f32x4){0.f, 0.f, 0.f, 0.f};
#pragma unroll
    for (int kh2 = 0; kh2 < 2; ++kh2) {
      bf16x8 qh, ql;
      split8p(&qs[fr][kh2 * 32 + fq * 8], qh, ql);
      bf16x8 sh = *(const bf16x8*)&sst_h[kh2 * 4 + fq][(e0 + fr) * 8];
      bf16x8 sl = *(const bf16x8*)&sst_l[kh2 * 4 + fq][(e0 + fr) * 8];
      o2 = __builtin_amdgcn_mfma_f32_16x16x32_bf16(qh, sh, o2, 0, 0, 0);
      o2 = __builtin_amdgcn_mfma_f32_16x16x32_bf16(qh, sl, o2, 0, 0, 0);
      o2 = __builtin_amdgcn_mfma_f32_16x16x32_bf16(ql, sh, o2, 0, 0, 0);
      if (kh2 < khmax) {
        bf16x8 ph = *(const bf16x8*)&pa_h[kh2 * 4 + fq][fr * 8];
        bf16x8 pl = *(const bf16x8*)&pa_l[kh2 * 4 + fq][fr * 8];
        bf16x8 bvv = *(const bf16x8*)&vst[e0 + fr][kh2 * 32 + fq * 8];
        o1 = __builtin_amdgcn_mfma_f32_16x16x32_bf16(ph, bvv, o1, 0, 0, 0);
        o1 = __builtin_amdgcn_mfma_f32_16x16x32_bf16(pl, bvv, o1, 0, 0, 0);
      }
    }
    float ofin[4], ssp[4];
#pragma unroll
    for (int r = 0; r < 4; ++r) {
      int gi = gi0 + fq * 4 + r;
      ofin[r] = o1[r] + dpow[gi + 1] * o2[r];
      ssp[r] = ofin[r] * ofin[r];
    }
#pragma unroll
    for (int r = 0; r < 4; ++r) {
      ssp[r] += __shfl_xor(ssp[r], 1, 64);
      ssp[r] += __shfl_xor(ssp[r], 2, 64);
      ssp[r] += __shfl_xor(ssp[r], 4, 64);
      ssp[r] += __shfl_xor(ssp[r], 8, 64);
    }
    if (fr == 0) {
#pragma unroll
      for (int r = 0; r < 4; ++r) ssred[w][fq * 4 + r] = ssp[r];
    }
    bar_lds();                                    // [C] keeps prefetch in flight
    // ---- phase 4: rms + gate + og store; waves 4-7 publish new S to sst ----
#pragma unroll
    for (int r = 0; r < 4; ++r) {
      int i16 = fq * 4 + r;
      float tot = 0.f;
#pragma unroll
      for (int w2 = 0; w2 < 8; ++w2) tot += ssred[w2][i16];
      float rms = rsqrtf(tot * (1.f / 128.f) + 1e-5f);
      int grow = rowbase + gi0 + i16;
      float g = bf2f(vg[(size_t)grow * 4096 + 2048 + h * 128 + e0 + fr]);
      float y = ofin[r] * rms * gww * (g / (1.f + expf(-g)));
      og[(size_t)grow * 2048 + h * 128 + e0 + fr] = f2bf(y);
    }
    if (w >= 4 && n < 31) {
      int eb = (w - 4) * 32;
#pragma unroll
      for (int dt = 0; dt < 4; ++dt) {
        int g = dt * 2 + (fq >> 1);
#pragma unroll
        for (int nt = 0; nt < 2; ++nt) {
          int e = eb + nt * 16 + fr;
          ushort4 wh, wl;
#pragma unroll
          for (int r = 0; r < 4; ++r) {
            union { float f; u32 u; } c; c.f = Sacc[dt][nt][r];
            union { u32 u; float f; } hf; hf.u = c.u & 0xffff0000u;
            union { float f; u32 u; } lw; lw.f = Sacc[dt][nt][r] - hf.f;
            ((u16*)&wh)[r] = (u16)(c.u >> 16);
            ((u16*)&wl)[r] = (u16)(lw.u >> 16);
          }
          int idx = e * 8 + (fq & 1) * 4;
          *(ushort4*)&sst_h[g][idx] = wh;
          *(ushort4*)&sst_l[g][idx] = wl;
        }
      }
    }
    // next loop-top __syncthreads separates these sst writes from next phase-3 reads
  }
}

extern "C" void kernel_launch(void* const* d_in, const int* in_sizes, int n_in,
                              void* d_out, int out_size, void* d_ws, size_t ws_size,
                              hipStream_t stream) {
  const float* x   = (const float*)d_in[0];
  const float* Wq  = (const float*)d_in[1];
  const float* Wk  = (const float*)d_in[2];
  const float* Wv  = (const float*)d_in[3];
  const float* Wg  = (const float*)d_in[4];
  const float* Wo  = (const float*)d_in[5];
  const float* gnw = (const float*)d_in[6];
  float* out = (float*)d_out;

  const size_t MB = 1024 * 1024;
  char* ws = (char*)d_ws;
  u16*  xb   = (u16*)(ws + 0 * MB);
  u16*  Wqkb = (u16*)(ws + 16 * MB);
  u16*  Wvgb = (u16*)(ws + 20 * MB);
  float* qk  = (float*)(ws + 32 * MB);
  u16*  vg   = (u16*)(ws + 96 * MB);
  u16*  Wob  = (u16*)(ws + 160 * MB);
  u16*  og   = (u16*)(ws + 0 * MB);   // overlay (xb/Wqkb/Wvgb dead by then)
  const size_t NEED = 164 * MB;
  if (ws_size < NEED) {
    k_sentinel<<<1, 64, 0, stream>>>(out);
    return;
  }

  k_cvt_x<<<8192, 256, 0, stream>>>(x, xb);
  k_transpose<<<dim3(32, 32), 256, 0, stream>>>(Wq, Wqkb, 1024, 1024);
  k_transpose<<<dim3(32, 32), 256, 0, stream>>>(Wk, Wqkb + (size_t)1024 * 1024, 1024, 1024);
  k_transpose<<<dim3(64, 32), 256, 0, stream>>>(Wv, Wvgb, 1024, 2048);
  k_transpose<<<dim3(64, 32), 256, 0, stream>>>(Wg, Wvgb + (size_t)2048 * 1024, 1024, 2048);
  k_transpose<<<dim3(32, 64), 256, 0, stream>>>(Wo, Wob, 2048, 1024);

  k_gemm<false><<<dim3(16, 64), 256, 0, stream>>>(xb, Wqkb, qk, 2048, 1024);  // qk f32
  k_gemm<true ><<<dim3(32, 64), 256, 0, stream>>>(xb, Wvgb, vg, 4096, 1024);  // v|g bf16
  k_rope<<<1024, 256, 0, stream>>>(qk);
  k_retention<<<256, 512, 0, stream>>>(qk, vg, gnw, og);
  k_gemm<false><<<dim3(8, 64), 256, 0, stream>>>(og, Wob, out, 1024, 2048);   // out f32
}